// Round 5
// baseline (158.492 us; speedup 1.0000x reference)
//
#include <hip/hip_runtime.h>
#include <math.h>

// Problem constants: B=32, E=1024, H=1024, N=128, L=64, K=8
#define NB 32
#define NE 1024
#define NH 1024
#define NN 128
#define NL 64
#define NK 8
#define GS 8     // g-chunks for qk partial sums
#define NBLK 256 // persistent blocks (1 per CU nominally)
#define BS 512   // threads per block (8 waves)

__device__ __forceinline__ float dot4f(float4 a, float4 b) {
    return a.x * b.x + a.y * b.y + a.z * b.z + a.w * b.w;
}

// ---------------------------------------------------------------------------
// Grid barrier: capacity-safe (grid fits device 4x over even when packed),
// agent-scope acq/rel; cnt/gen zeroed by hipMemsetAsync before each launch.
// ---------------------------------------------------------------------------
__device__ __forceinline__ void grid_barrier(int* cnt, int* gen, int target) {
    __syncthreads();
    if (threadIdx.x == 0) {
        __threadfence();
        int prev = __hip_atomic_fetch_add(cnt, 1, __ATOMIC_ACQ_REL,
                                          __HIP_MEMORY_SCOPE_AGENT);
        if (prev == NBLK - 1) {
            __hip_atomic_store(cnt, 0, __ATOMIC_RELAXED, __HIP_MEMORY_SCOPE_AGENT);
            __hip_atomic_fetch_add(gen, 1, __ATOMIC_RELEASE,
                                   __HIP_MEMORY_SCOPE_AGENT);
        } else {
            while (__hip_atomic_load(gen, __ATOMIC_ACQUIRE,
                                     __HIP_MEMORY_SCOPE_AGENT) < target)
                __builtin_amdgcn_s_sleep(2);
        }
        __threadfence();
    }
    __syncthreads();
}

// ---------------------------------------------------------------------------
// rowdot8: one wave computes dot(W[o,:], A[b,:]) + bias[o] for 8 consecutive b
// ---------------------------------------------------------------------------
template <int D>
__device__ void rowdot8(const float* __restrict__ A, const float* __restrict__ W,
                        const float* __restrict__ bias, float* __restrict__ C,
                        int wid) {
    int lane = threadIdx.x & 63;
    int o  = wid >> 2;          // 0..1023
    int b0 = (wid & 3) * 8;     // batch group of 8
    const float4* Wr = (const float4*)(W + (size_t)o * D);
    const float4* Ar[8];
#pragma unroll
    for (int i = 0; i < 8; ++i) Ar[i] = (const float4*)(A + (size_t)(b0 + i) * D);
    float acc[8] = {0.f, 0.f, 0.f, 0.f, 0.f, 0.f, 0.f, 0.f};
#pragma unroll
    for (int c = 0; c < D / 256; ++c) {
        float4 w4 = Wr[c * 64 + lane];
#pragma unroll
        for (int i = 0; i < 8; ++i) acc[i] += dot4f(w4, Ar[i][c * 64 + lane]);
    }
#pragma unroll
    for (int s = 32; s; s >>= 1)
#pragma unroll
        for (int i = 0; i < 8; ++i) acc[i] += __shfl_down(acc[i], s, 64);
    if (lane == 0) {
        float bb = bias[o];
#pragma unroll
        for (int i = 0; i < 8; ++i) C[(size_t)(b0 + i) * NH + o] = acc[i] + bb;
    }
}

// ---------------------------------------------------------------------------
// MEGA: all five stages in one persistent kernel, 4 grid barriers.
// ---------------------------------------------------------------------------
__global__ __launch_bounds__(BS)
void mega_kernel(const float* __restrict__ inputs,
                 const float* __restrict__ Wq,  const float* __restrict__ bq,
                 const float* __restrict__ Wk,
                 const float* __restrict__ Wc,  const float* __restrict__ bc,
                 const float* __restrict__ cache_keys,
                 const float* __restrict__ cache_values,
                 float* __restrict__ out,
                 float* __restrict__ scores, float* __restrict__ query,
                 float* __restrict__ pqk,    float* __restrict__ patt,
                 float* __restrict__ F,      float* __restrict__ weights,
                 int* __restrict__ top_idx,  int* __restrict__ bar) {
    __shared__ float qlds[2][1024];   // 8KB  (P2, per half-block)
    __shared__ float red[2][2048];    // 16KB (P2)
    __shared__ float qk_lds[NH];      // 4KB  (P3)
    __shared__ float logits_s[NL];
    __shared__ float coef_s[NL];
    __shared__ float psum[2][NH];     // 8KB  (P3)

    int t = threadIdx.x, bid = blockIdx.x;
    int lane = t & 63;
    int gw = bid * 8 + (t >> 6);      // global wave id, 0..2047
    int* cnt = bar;
    int* gen = bar + 32;              // separate cache line

    // ---- P1: scores (4096 wave-units) + query rowdot (4096 wave-units) ----
    for (int u = gw; u < 8192; u += 2048) {
        if (u < 4096) {
            int b = u >> 7, n = u & 127;
            const float4* ck = (const float4*)(cache_keys + ((size_t)b * NN + n) * NE);
            const float4* in = (const float4*)(inputs + (size_t)b * NE);
            float acc = 0.f;
#pragma unroll
            for (int c = 0; c < 4; ++c) acc += dot4f(ck[c * 64 + lane], in[c * 64 + lane]);
#pragma unroll
            for (int s = 32; s; s >>= 1) acc += __shfl_down(acc, s, 64);
            if (lane == 0) scores[(u >> 7) * NN + n] = acc;
        } else {
            rowdot8<1024>(inputs, Wq, bq, query, u - 4096);
        }
    }
    grid_barrier(cnt, gen, 1);

    // ---- P2: pqk tiles (1024 units) + topk (32 units), half-block units ----
    // pqk[gs][b][h] = sum_{g in chunk of 128} query[b,g]*Wk[g,h]
    // (bk dropped: q·bk constant over l -> cancels in the l-softmax)
    {
        int hb = t >> 8, tt = t & 255;
        for (int i = 0; i < 3; ++i) {
            int u = bid * 2 + hb + i * 512;
            bool pq = (u < 1024);
            int gs = u & 7, hs = (u >> 3) & 31, bg = u >> 8, b0 = bg * 8;
            if (pq) {
#pragma unroll
                for (int j = 0; j < 4; ++j) {
                    int idx = tt * 4 + j;
                    int g = idx >> 3, bj = idx & 7;
                    qlds[hb][idx] = query[(size_t)(b0 + bj) * NH + gs * 128 + g];
                }
            }
            __syncthreads();
            if (pq) {
                int h_local = tt & 31, g_lane = tt >> 5;
                int h = hs * 32 + h_local;
                float acc[8] = {0.f, 0.f, 0.f, 0.f, 0.f, 0.f, 0.f, 0.f};
#pragma unroll
                for (int ii = 0; ii < 16; ++ii) {
                    int g_local = g_lane * 16 + ii;
                    float w = Wk[(size_t)(gs * 128 + g_local) * NH + h];
                    float4 q0 = *(const float4*)&qlds[hb][g_local * 8];
                    float4 q1 = *(const float4*)&qlds[hb][g_local * 8 + 4];
                    acc[0] += q0.x * w; acc[1] += q0.y * w;
                    acc[2] += q0.z * w; acc[3] += q0.w * w;
                    acc[4] += q1.x * w; acc[5] += q1.y * w;
                    acc[6] += q1.z * w; acc[7] += q1.w * w;
                }
                *(float4*)&red[hb][(g_lane * 32 + h_local) * 8]     = *(float4*)&acc[0];
                *(float4*)&red[hb][(g_lane * 32 + h_local) * 8 + 4] = *(float4*)&acc[4];
            } else if (u < 1056 && tt < 64) {
                // register-only topk: butterfly leaves winner in every lane
                int b = u - 1024;
                float s0 = scores[b * NN + tt];
                float s1 = scores[b * NN + 64 + tt];
                float tvr[NK]; int tir[NK];
#pragma unroll
                for (int kk = 0; kk < NK; ++kk) {
                    float v = s0; int idx = tt;
                    if (s1 > v) { v = s1; idx = tt + 64; }
#pragma unroll
                    for (int s = 1; s < 64; s <<= 1) {
                        float ov = __shfl_xor(v, s, 64);
                        int   oi = __shfl_xor(idx, s, 64);
                        if (ov > v || (ov == v && oi < idx)) { v = ov; idx = oi; }
                    }
                    tvr[kk] = v; tir[kk] = idx;
                    if (idx == tt)      s0 = -INFINITY;
                    if (idx == tt + 64) s1 = -INFINITY;
                }
                if (tt == 0) {
                    float sum = 0.f;
#pragma unroll
                    for (int kk = 0; kk < NK; ++kk) sum += __expf(tvr[kk] - tvr[0]);
#pragma unroll
                    for (int kk = 0; kk < NK; ++kk) {
                        weights[b * NK + kk] = __expf(tvr[kk] - tvr[0]) / sum;
                        top_idx[b * NK + kk] = tir[kk];
                    }
                }
            }
            __syncthreads();
            if (pq) {
                int bj = tt >> 5, hl = tt & 31;
                float ssum = 0.f;
#pragma unroll
                for (int gl = 0; gl < 8; ++gl) ssum += red[hb][(gl * 32 + hl) * 8 + bj];
                pqk[((size_t)gs * NB + b0 + bj) * NH + hs * 32 + hl] = ssum;
            }
        }
    }
    grid_barrier(cnt, gen, 2);

    // ---- P3: attention, one (b,k) per block, 8 waves ----
    {
        int b = bid >> 3, k = bid & 7;
        if (t < 256) {
            float4 s = make_float4(0.f, 0.f, 0.f, 0.f);
#pragma unroll
            for (int gs = 0; gs < GS; ++gs) {
                float4 p = ((const float4*)pqk)[((size_t)gs * NB + b) * 256 + t];
                s.x += p.x; s.y += p.y; s.z += p.z; s.w += p.w;
            }
            ((float4*)qk_lds)[t] = s;
        }
        __syncthreads();

        int wv = t >> 6;
        int zi = top_idx[b * NK + k];
        const float* zbase = cache_values + (((size_t)b * NN + zi) * NL) * NH;

        // logits: 8 waves x 8 rows
        {
            float4 qk[4];
#pragma unroll
            for (int c = 0; c < 4; ++c) qk[c] = ((const float4*)qk_lds)[c * 64 + lane];
            for (int r = 0; r < 8; ++r) {
                int l = wv * 8 + r;
                const float4* zr = (const float4*)(zbase + (size_t)l * NH);
                float dot = 0.f;
#pragma unroll
                for (int c = 0; c < 4; ++c) dot += dot4f(zr[c * 64 + lane], qk[c]);
#pragma unroll
                for (int s = 32; s; s >>= 1) dot += __shfl_down(dot, s, 64);
                if (lane == 0) logits_s[l] = dot * 0.03125f;   // 1/sqrt(1024)
            }
        }
        __syncthreads();
        // softmax over l, retrieval weight folded
        if (t < 64) {
            float v = logits_s[t];
            float m = v;
#pragma unroll
            for (int s = 1; s < 64; s <<= 1) m = fmaxf(m, __shfl_xor(m, s, 64));
            float e = __expf(v - m);
            float sum = e;
#pragma unroll
            for (int s = 1; s < 64; s <<= 1) sum += __shfl_xor(sum, s, 64);
            coef_s[t] = weights[b * NK + k] * e / sum;
        }
        __syncthreads();
        // PV: group g (256 threads) sums rows [g*32, g*32+32)
        {
            int grp = t >> 8, tt = t & 255;
            float4 acc = make_float4(0.f, 0.f, 0.f, 0.f);
            for (int rr = 0; rr < 32; ++rr) {
                int l = grp * 32 + rr;
                float c = coef_s[l];
                float4 z = ((const float4*)(zbase + (size_t)l * NH))[tt];
                acc.x += c * z.x; acc.y += c * z.y; acc.z += c * z.z; acc.w += c * z.w;
            }
            ((float4*)psum[grp])[tt] = acc;
        }
        __syncthreads();
        if (t < 256) {
            float4 a = ((const float4*)psum[0])[t];
            float4 b4 = ((const float4*)psum[1])[t];
            a.x += b4.x; a.y += b4.y; a.z += b4.z; a.w += b4.w;
            ((float4*)patt)[((size_t)b * NK + k) * 256 + t] = a;
        }
    }
    grid_barrier(cnt, gen, 3);

    // ---- P4: buildF (32 blocks; thread t owns float4 j4=t of F row b) ----
    if (bid < 32) {
        int b = bid, j4 = t;
        float4 v;
        if (j4 < 256) {
            v = make_float4(0.f, 0.f, 0.f, 0.f);
#pragma unroll
            for (int k = 0; k < NK; ++k) {
                float4 p = ((const float4*)patt)[((size_t)b * NK + k) * 256 + j4];
                v.x += p.x; v.y += p.y; v.z += p.z; v.w += p.w;
            }
        } else {
            v = ((const float4*)(inputs + (size_t)b * NE))[j4 - 256];
        }
        ((float4*)F)[(size_t)b * 512 + j4] = v;
    }
    grid_barrier(cnt, gen, 4);

    // ---- P5: out = F @ Wc^T + bc (4096 wave-units) ----
    for (int u = gw; u < 4096; u += 2048)
        rowdot8<2048>(F, Wc, bc, out, u);
}

// ---------------------------------------------------------------------------
extern "C" void kernel_launch(void* const* d_in, const int* in_sizes, int n_in,
                              void* d_out, int out_size, void* d_ws, size_t ws_size,
                              hipStream_t stream) {
    const float* inputs       = (const float*)d_in[0];
    const float* Wq           = (const float*)d_in[1];
    const float* bq           = (const float*)d_in[2];
    const float* Wk           = (const float*)d_in[3];
    // d_in[4] = bk: cancels in the l-softmax (constant over l)
    const float* Wc           = (const float*)d_in[5];
    const float* bc           = (const float*)d_in[6];
    const float* cache_keys   = (const float*)d_in[7];
    const float* cache_values = (const float*)d_in[8];
    float* out = (float*)d_out;

    float* ws      = (float*)d_ws;
    float* scores  = ws;                       // 4096
    float* query   = scores + 4096;            // 32768
    float* pqk     = query + 32768;            // 8*32*1024 = 262144
    float* patt    = pqk + 262144;             // 32*8*1024 = 262144
    float* F       = patt + 262144;            // 65536
    float* weights = F + 65536;                // 256
    int*   tidx    = (int*)(weights + 256);    // 256 ints
    int*   bar     = tidx + 256;               // barrier state (cnt, gen)
    (void)ws_size; (void)n_in; (void)in_sizes; (void)out_size;

    hipMemsetAsync(bar, 0, 256, stream);
    mega_kernel<<<NBLK, BS, 0, stream>>>(inputs, Wq, bq, Wk, Wc, bc,
                                         cache_keys, cache_values, out,
                                         scores, query, pqk, patt, F,
                                         weights, tidx, bar);
}